// Round 17
// baseline (2156.736 us; speedup 1.0000x reference)
//
#include <hip/hip_runtime.h>
#include <stdint.h>
#include <math.h>

#define S_ 4096
#define D_ 1024
#define I_ 4096
#define C_ 1024
#define L_ 4

typedef unsigned short u16;
typedef short bf16x8 __attribute__((ext_vector_type(8)));
typedef float f32x4 __attribute__((ext_vector_type(4)));
typedef float f32x2 __attribute__((ext_vector_type(2)));

__device__ __forceinline__ u16 f2bf(float f) {
  union { float f; uint32_t u; } c; c.f = f;
  return (u16)((c.u + 0x7FFFu + ((c.u >> 16) & 1u)) >> 16);
}
__device__ __forceinline__ float bf2f(u16 b) {
  union { uint32_t u; float f; } c; c.u = (uint32_t)b << 16;
  return c.f;
}
__device__ __forceinline__ u16 f2h(float f) {
  _Float16 h = (_Float16)f;
  return *(u16*)&h;
}
__device__ __forceinline__ float h2f(u16 b) {
  _Float16 h = *(_Float16*)&b;
  return (float)h;
}
__device__ __forceinline__ float h2f_lo(uint32_t u) { return h2f((u16)(u & 0xffffu)); }
__device__ __forceinline__ float h2f_hi(uint32_t u) { return h2f((u16)(u >> 16)); }

__device__ __forceinline__ void gll16(const void* g, void* l) {
  __builtin_amdgcn_global_load_lds(
      (__attribute__((address_space(1))) void*)(g),
      (__attribute__((address_space(3))) void*)(l), 16, 0, 0);
}

#define BAR() asm volatile("s_barrier" ::: "memory")
#define WAITV(n) asm volatile("s_waitcnt vmcnt(" #n ")" ::: "memory")

// bijective XCD swizzle (m204)
__device__ __forceinline__ int xcd_swz(int orig, int nwg) {
  int q8 = nwg >> 3, r8 = nwg & 7;
  int xcd = orig & 7, rem = orig >> 3;
  return (xcd < r8 ? xcd * (q8 + 1) : r8 * (q8 + 1) + (xcd - r8) * q8) + rem;
}

// triangular tile decode: tidx -> (br, bc), bc <= br
__device__ __forceinline__ void tri_decode(int tidx, int& br, int& bc) {
  br = (int)((sqrtf(8.0f * (float)tidx + 1.0f) - 1.0f) * 0.5f);
  while ((br + 1) * (br + 2) / 2 <= tidx) ++br;
  while (br * (br + 1) / 2 > tidx) --br;
  bc = tidx - br * (br + 1) / 2;
}

// ---------------- 256x256 8-phase body (T1+T2+T3+T4+T5) ----------------
// 512 threads = 8 waves (2M x 4N), per-wave C = 128x64, BK = 64.
// LDS: A[2 par][2 half][128x64], B same = 128 KiB. XOR-octet swizzle.
// NOTE: 128 KiB LDS -> 1 block/CU; dispatch wall = ceil(nblocks/256) rounds.
// Window t: ph1 stages B-h1(t+1); ph2: A-h0(t+2); ph3: A-h1(t+2); ph4: B-h0(t+2).
// vmcnt(6) at window boundary retires through B-h1(t+1). Requires t1-t0 >= 2.
// Outputs (u16 only): outU row-major (bf16 if isBF else f16) via LDS-bounce
// coalesced epilogue, or outT: bf16 TRANSPOSED (outT[col][row], ld=ldT).
// CALLER NOTE: epilogue reads LDS; a __syncthreads() is required between
// consecutive body calls in one kernel (next prologue overwrites LDS).
__device__ __forceinline__ void gemm256_body(
    u16* sA, u16* sB,
    const u16* __restrict__ A, const u16* __restrict__ Bt,
    const float* __restrict__ bias,
    u16* __restrict__ outU, int isBF,
    u16* __restrict__ outT, int ldT,
    int N, int K, float scale, int relu,
    int row0, int col0, int t0, int t1)
{
  int tid = threadIdx.x, l = tid & 63;
  int w = tid >> 6;
  int wr = w >> 2, wc = w & 3;
  int lrow = l & 15, lq = l >> 4;
  int hb = wc >> 1;
  int rx = lrow & 7;

  const u16* ap[2]; const u16* bp[2]; int dst[2];
#pragma unroll
  for (int u = 0; u < 2; ++u) {
    int c = u * 512 + tid;
    int row = c >> 3;
    int oct = (c & 7) ^ (row & 7);
    ap[u] = A + (size_t)(row0 + row) * K + oct * 8;
    bp[u] = Bt + (size_t)(col0 + row) * K + oct * 8;
    dst[u] = c * 8;
  }

#define STAGE_A(par, hh, t)                                                     \
  { _Pragma("unroll") for (int u = 0; u < 2; ++u)                               \
      gll16(ap[u] + (size_t)(hh) * 128 * K + (t) * 64,                          \
            &sA[((par) * 2 + (hh)) * 8192 + dst[u]]); }
#define STAGE_B(par, hh, t)                                                     \
  { _Pragma("unroll") for (int u = 0; u < 2; ++u)                               \
      gll16(bp[u] + (size_t)(hh) * 128 * K + (t) * 64,                          \
            &sB[((par) * 2 + (hh)) * 8192 + dst[u]]); }
#define LD_A(DST, par, mh)                                                      \
  { _Pragma("unroll") for (int mi = 0; mi < 4; ++mi)                            \
    _Pragma("unroll") for (int kc = 0; kc < 2; ++kc)                            \
      DST[mi][kc] = *(const bf16x8*)&sA[((par) * 2 + wr) * 8192 +               \
          ((mh) * 64 + mi * 16 + lrow) * 64 + (((kc * 4 + lq) ^ rx) * 8)]; }
#define LD_B(DST, par, nh)                                                      \
  { _Pragma("unroll") for (int nj = 0; nj < 2; ++nj)                            \
    _Pragma("unroll") for (int kc = 0; kc < 2; ++kc)                            \
      DST[nj][kc] = *(const bf16x8*)&sB[((par) * 2 + hb) * 8192 +               \
          ((wc & 1) * 64 + (nh) * 32 + nj * 16 + lrow) * 64 +                   \
          (((kc * 4 + lq) ^ rx) * 8)]; }

  f32x4 acc[8][4];
#pragma unroll
  for (int i = 0; i < 8; ++i)
#pragma unroll
    for (int j = 0; j < 4; ++j) {
      acc[i][j][0] = 0.f; acc[i][j][1] = 0.f; acc[i][j][2] = 0.f; acc[i][j][3] = 0.f;
    }

#define MM(AF, MB, NB)                                                          \
  { __builtin_amdgcn_s_setprio(1);                                             \
    _Pragma("unroll") for (int kc = 0; kc < 2; ++kc)                            \
    _Pragma("unroll") for (int mi = 0; mi < 4; ++mi)                            \
    _Pragma("unroll") for (int nj = 0; nj < 2; ++nj)                            \
      acc[(MB) + mi][(NB) + nj] = __builtin_amdgcn_mfma_f32_16x16x32_bf16(      \
          AF[mi][kc], bfv[nj][kc], acc[(MB) + mi][(NB) + nj], 0, 0, 0);         \
    __builtin_amdgcn_s_setprio(0); }

  bf16x8 afA[4][2], afB[4][2], bfv[2][2];

  STAGE_A(0, 0, t0); STAGE_A(0, 1, t0); STAGE_B(0, 0, t0); STAGE_B(0, 1, t0);
  STAGE_A(1, 0, t0 + 1); STAGE_A(1, 1, t0 + 1); STAGE_B(1, 0, t0 + 1);
  WAITV(6);
  BAR();

  for (int t = t0; t < t1; ++t) {
    int p = (t - t0) & 1;
    LD_A(afA, p, 0);
    LD_B(bfv, p, 0);
    LD_A(afB, p, 1);
    if (t + 1 < t1) STAGE_B(p ^ 1, 1, t + 1);
    BAR();
    MM(afA, 0, 0);
    BAR();
    if (t + 2 < t1) STAGE_A(p, 0, t + 2);
    BAR();
    MM(afB, 4, 0);
    BAR();
    LD_B(bfv, p, 1);
    if (t + 2 < t1) STAGE_A(p, 1, t + 2);
    BAR();
    MM(afB, 4, 2);
    BAR();
    if (t + 2 < t1) STAGE_B(p, 0, t + 2);
    BAR();
    MM(afA, 0, 2);
    if (t + 2 < t1) { WAITV(6); } else { WAITV(0); }
    BAR();
  }
#undef STAGE_A
#undef STAGE_B
#undef LD_A
#undef LD_B
#undef MM

  float biasv[4] = {0.f, 0.f, 0.f, 0.f};
  if (bias) {
#pragma unroll
    for (int j = 0; j < 4; ++j) biasv[j] = bias[col0 + wc * 64 + j * 16 + lrow];
  }

  if (outT) {
    // transposed bf16 epilogue via LDS bounce (verified round 10).
    u16* tlds = sA;  // [128 cols][264 rows]
    int myhalf = wc >> 1;
    int colb = tid >> 5;
    int sub = tid & 31;
#pragma unroll
    for (int half = 0; half < 2; ++half) {
      BAR();
      if (myhalf == half) {
#pragma unroll
        for (int i = 0; i < 8; ++i)
#pragma unroll
          for (int r = 0; r < 4; ++r)
#pragma unroll
            for (int j = 0; j < 4; ++j) {
              int cl = (wc * 64 + j * 16 + lrow) & 127;
              int rowl = wr * 128 + i * 16 + lq * 4 + r;
              tlds[cl * 264 + rowl] = f2bf(acc[i][j][r] + biasv[j]);
            }
      }
      BAR();
#pragma unroll
      for (int it = 0; it < 8; ++it) {
        int cl = it * 16 + colb;
        size_t gb = (size_t)(col0 + half * 128 + cl) * ldT + row0 + sub * 8;
        bf16x8 v = *(const bf16x8*)&tlds[cl * 264 + sub * 8];
        *(bf16x8*)&outT[gb] = v;
      }
    }
    return;
  }

  // row-major u16 epilogue via LDS bounce
  u16* tlds = sA;
  int rl0 = tid >> 5;   // 0..15
  int ch = tid & 31;    // 0..31
#pragma unroll
  for (int half = 0; half < 2; ++half) {
    BAR();
    if (wr == half) {
#pragma unroll
      for (int i = 0; i < 8; ++i)
#pragma unroll
        for (int r = 0; r < 4; ++r)
#pragma unroll
          for (int j = 0; j < 4; ++j) {
            int rowl = i * 16 + lq * 4 + r;
            int cl = wc * 64 + j * 16 + lrow;
            float v = acc[i][j][r] * scale + biasv[j];
            if (relu) v = fmaxf(v, 0.f);
            tlds[rowl * 264 + cl] = isBF ? f2bf(v) : f2h(v);
          }
    }
    BAR();
#pragma unroll
    for (int it = 0; it < 8; ++it) {
      int rowl = it * 16 + rl0;
      size_t gb = (size_t)(row0 + half * 128 + rowl) * N + col0 + ch * 8;
      bf16x8 v = *(const bf16x8*)&tlds[rowl * 264 + ch * 8];
      *(bf16x8*)&outU[gb] = v;
    }
  }
}

// plain / K-ranged (flags: 1 relu), K-range [k0,k1), bf16 out
__global__ __launch_bounds__(512, 2) void gemm256k(
    const u16* __restrict__ A, const u16* __restrict__ Bt,
    const float* __restrict__ bias, u16* __restrict__ outB,
    int M, int N, int K, float scale, int flags, int k0, int k1)
{
  extern __shared__ char smem[];
  int wg = xcd_swz(blockIdx.x, gridDim.x);
  int nbx = N / 256;
  int br = wg / nbx, bc = wg % nbx;
  gemm256_body((u16*)smem, (u16*)smem + 32768, A, Bt, bias, outB, 1,
               nullptr, 0, N, K, scale, flags & 1, br * 256, bc * 256,
               k0 / 64, k1 / 64);
}

// fused QKV 3-in-1: grid 256 (1 perfect round); each block computes its
// (br,bc) tile for Q, K, then V (V emitted TRANSPOSED to vT). A-panel is
// L2-hot for the 2nd/3rd pass. __syncthreads() between passes: the epilogue's
// LDS-bounce reads must retire before the next prologue's gll16 overwrites.
struct B3 { const float* b[3]; };
__global__ __launch_bounds__(512, 2) void gemm256_qkv(
    const u16* __restrict__ A, const u16* __restrict__ BtBase,
    B3 b3, u16* __restrict__ outQK, u16* __restrict__ vT, int K)
{
  extern __shared__ char smem[];
  int wg = xcd_swz(blockIdx.x, gridDim.x);
  int br = wg >> 4, bc = wg & 15;
#pragma unroll 1
  for (int z = 0; z < 2; ++z) {
    gemm256_body((u16*)smem, (u16*)smem + 32768, A,
                 BtBase + (size_t)z * I_ * D_, b3.b[z],
                 outQK + (size_t)z * S_ * I_, 1, nullptr, 0,
                 I_, K, 1.0f, 0, br * 256, bc * 256, 0, K / 64);
    __syncthreads();
  }
  gemm256_body((u16*)smem, (u16*)smem + 32768, A,
               BtBase + (size_t)2 * I_ * D_, b3.b[2],
               nullptr, 1, vT, S_,
               I_, K, 1.0f, 0, br * 256, bc * 256, 0, K / 64);
}

// triangular causal scores, balanced 512-block split (r13/r14): tiles 0..103
// 4-way (16 kt, p0..p3); tiles 104..135 3-way (21/21/22 kt, p0..p2).
// Only tile 104 (br13 diag) needs its p3 rect zeroed (rows>=3584 are all
// 3-way and softmax skips p3 there). 3-way blocks interleaved 6-per-32-wg.
__global__ __launch_bounds__(512, 2) void gemm256_tri(
    const u16* __restrict__ A, const u16* __restrict__ Bt,
    u16* __restrict__ p0, u16* __restrict__ p1, u16* __restrict__ p2,
    u16* __restrict__ p3, int K, float scale)
{
  extern __shared__ char smem[];
  int wg = xcd_swz(blockIdx.x, gridDim.x);   // grid 512
  int c32 = wg >> 5, off = wg & 31;
  int tidx, t0, t1;
  u16* o;
  if (off < 6) {
    int i3 = c32 * 6 + off;        // 0..95
    tidx = 104 + i3 / 3;
    int chk = i3 % 3;
    t0 = (chk == 0) ? 0 : (chk == 1 ? 21 : 42);
    t1 = (chk == 0) ? 21 : (chk == 1 ? 42 : 64);
    o = (chk == 0) ? p0 : (chk == 1 ? p1 : p2);
  } else {
    int i4 = c32 * 26 + (off - 6); // 0..415
    tidx = i4 >> 2;
    int chk = i4 & 3;
    t0 = chk * 16; t1 = t0 + 16;
    o = (chk == 0) ? p0 : (chk == 1 ? p1 : (chk == 2 ? p2 : p3));
  }
  int br, bc;
  tri_decode(tidx, br, bc);
  gemm256_body((u16*)smem, (u16*)smem + 32768, A, Bt, nullptr,
               o, 0, nullptr, 0,
               S_, K, scale, 0, br * 256, bc * 256, t0, t1);
}

// PV hybrid, LPT-ordered (longest blocks first).
__global__ __launch_bounds__(512, 2) void gemm256_pv(
    const u16* __restrict__ A, const u16* __restrict__ Bt,
    u16* __restrict__ outB, u16* __restrict__ pvH)
{
  extern __shared__ char smem[];
  int wg = xcd_swz(blockIdx.x, gridDim.x);   // grid 384
  int s0, br, dir;
  if      (wg < 32)  { s0 = 0;   br = 15; dir = 0; }
  else if (wg < 48)  { s0 = 32;  br = 7;  dir = 1; }
  else if (wg < 80)  { s0 = 48;  br = 14; dir = 0; }
  else if (wg < 112) { s0 = 80;  br = 13; dir = 0; }
  else if (wg < 128) { s0 = 112; br = 6;  dir = 1; }
  else if (wg < 160) { s0 = 128; br = 12; dir = 0; }
  else if (wg < 192) { s0 = 160; br = 11; dir = 0; }
  else if (wg < 208) { s0 = 192; br = 5;  dir = 1; }
  else if (wg < 240) { s0 = 208; br = 10; dir = 0; }
  else if (wg < 272) { s0 = 240; br = 9;  dir = 0; }
  else if (wg < 288) { s0 = 272; br = 4;  dir = 1; }
  else if (wg < 320) { s0 = 288; br = 8;  dir = 0; }
  else if (wg < 336) { s0 = 320; br = 3;  dir = 1; }
  else if (wg < 352) { s0 = 336; br = 2;  dir = 1; }
  else if (wg < 368) { s0 = 352; br = 1;  dir = 1; }
  else               { s0 = 368; br = 0;  dir = 1; }
  int u = wg - s0;
  if (dir) {
    int bc = u;
    gemm256_body((u16*)smem, (u16*)smem + 32768, A, Bt, nullptr,
                 outB, 1, nullptr, 0, I_, S_, 1.0f, 0,
                 br * 256, bc * 256, 0, (br + 1) * 4);
  } else {
    int bc = u >> 1;
    int chunk = u & 1;
    int lim = (br + 1) * 4;
    int half = lim >> 1;
    u16* o = pvH + (size_t)chunk * (S_ / 2) * I_ - (size_t)2048 * I_;
    gemm256_body((u16*)smem, (u16*)smem + 32768, A, Bt, nullptr,
                 o, 0, nullptr, 0, I_, S_, 1.0f, 0,
                 br * 256, bc * 256, chunk ? half : 0, chunk ? lim : half);
  }
}

// combine PV bottom-half f16 partials -> bf16
__global__ __launch_bounds__(256) void combine2pv(
    const u16* __restrict__ pvH, u16* __restrict__ outB)
{
  const int MN = (S_ / 2) * I_;
  int i = (blockIdx.x * 256 + threadIdx.x) * 4;
  ushort4 a = *(const ushort4*)&pvH[i];
  ushort4 b = *(const ushort4*)&pvH[MN + i];
  ushort4 o;
  o.x = f2bf(h2f(a.x) + h2f(b.x));
  o.y = f2bf(h2f(a.y) + h2f(b.y));
  o.z = f2bf(h2f(a.z) + h2f(b.z));
  o.w = f2bf(h2f(a.w) + h2f(b.w));
  *(ushort4*)&outB[(size_t)2048 * I_ + i] = o;
}

// 4-way K-split f16 partials: grid = ntiles*4
__global__ __launch_bounds__(512, 2) void gemm256_ks4(
    const u16* __restrict__ A, const u16* __restrict__ Bt,
    u16* __restrict__ pOut, int M, int N, int K)
{
  extern __shared__ char smem[];
  int wg = xcd_swz(blockIdx.x, gridDim.x);
  int chunk = wg & 3;
  int tile = wg >> 2;
  int nbx = N / 256;
  int br = tile / nbx, bc = tile % nbx;
  u16* o = pOut + (size_t)chunk * M * N;
  int kq = K / 4;
  gemm256_body((u16*)smem, (u16*)smem + 32768, A, Bt, nullptr,
               o, 0, nullptr, 0, N, K, 1.0f, 0,
               br * 256, bc * 256, (chunk * kq) / 64, ((chunk + 1) * kq) / 64);
}

// combine 4 f16 K-split partials + bias + bf16 resid -> bf16 (N power of 2)
__global__ __launch_bounds__(256) void combine4(
    const u16* __restrict__ p, const float* __restrict__ bias,
    const u16* __restrict__ residB, u16* __restrict__ outB, int MN, int N)
{
  int i = (blockIdx.x * 256 + threadIdx.x) * 4;
  ushort4 a = *(const ushort4*)&p[i];
  ushort4 b = *(const ushort4*)&p[MN + i];
  ushort4 c = *(const ushort4*)&p[2 * MN + i];
  ushort4 d = *(const ushort4*)&p[3 * MN + i];
  ushort4 rb = *(const ushort4*)&residB[i];
  f32x4 v;
  v[0] = h2f(a.x) + h2f(b.x) + h2f(c.x) + h2f(d.x) + bf2f(rb.x);
  v[1] = h2f(a.y) + h2f(b.y) + h2f(c.y) + h2f(d.y) + bf2f(rb.y);
  v[2] = h2f(a.z) + h2f(b.z) + h2f(c.z) + h2f(d.z) + bf2f(rb.z);
  v[3] = h2f(a.w) + h2f(b.w) + h2f(c.w) + h2f(d.w) + bf2f(rb.w);
  int col = i & (N - 1);
  v += *(const f32x4*)&bias[col];
  ushort4 o;
  o.x = f2bf(v[0]); o.y = f2bf(v[1]); o.z = f2bf(v[2]); o.w = f2bf(v[3]);
  *(ushort4*)&outB[i] = o;
}

// per-layer prep: z 0..5 weight transpose+convert (64x64 tiles);
// z==6 Wout transpose (layer 0 only, doWout flag); z==7 fillp3 (zero the p3
// rect of tile 104 only — br13 diag; rows>=3584 skip p3 in softmax).
struct T7 {
  const float* src[7];
  u16* dst[7];
};

__global__ __launch_bounds__(256) void prep_k(T7 a, u16* __restrict__ p3,
                                              int doWout) {
  int z = blockIdx.z;
  if (z == 7) {
    int b = blockIdx.y * gridDim.x + blockIdx.x;
    if (b >= 32) return;
    int row = 13 * 256 + b * 8 + (threadIdx.x >> 5);
    int col = 13 * 256 + (threadIdx.x & 31) * 8;
    ushort4 z4 = {0, 0, 0, 0};
    *(ushort4*)&p3[(size_t)row * S_ + col] = z4;
    *(ushort4*)&p3[(size_t)row * S_ + col + 4] = z4;
    return;
  }
  if (z == 6 && !doWout) return;
  __shared__ float tile[64][65];
  int R, C;
  if (z == 6) { R = D_; C = C_; }
  else if (z == 3 || z == 5) { R = I_; C = D_; }
  else { R = D_; C = I_; }
  int bid = blockIdx.y * gridDim.x + blockIdx.x;
  int nbx = C / 64;
  if (bid >= nbx * (R / 64)) return;
  int bx = bid % nbx, by = bid / nbx;
  const float* src = a.src[z];
  u16* dst = a.dst[z];
  int c0 = bx * 64, r0 = by * 64;
  int tx = threadIdx.x & 63, ty = threadIdx.x >> 6;
#pragma unroll
  for (int i = 0; i < 64; i += 4)
    tile[ty + i][tx] = src[(size_t)(r0 + ty + i) * C + c0 + tx];
  __syncthreads();
#pragma unroll
  for (int i = 0; i < 64; i += 4)
    dst[(size_t)(c0 + ty + i) * R + r0 + tx] = f2bf(tile[tx][ty + i]);
}

// embed: 8 elems/thread, bf16 out only
__global__ __launch_bounds__(256) void embed_k(const int* __restrict__ idx,
                                               const float* __restrict__ emb,
                                               const float* __restrict__ pos,
                                               u16* __restrict__ xb)
{
  int i = (blockIdx.x * 256 + threadIdx.x) * 8;
  int s = i >> 10;          // / D_
  int d = i & (D_ - 1);
  const float* e = emb + (size_t)idx[s] * D_ + d;
  const float* p = pos + (size_t)s * D_ + d;
  f32x4 v0 = *(const f32x4*)e + *(const f32x4*)p;
  f32x4 v1 = *(const f32x4*)(e + 4) + *(const f32x4*)(p + 4);
  ushort4 b0, b1;
  b0.x = f2bf(v0[0]); b0.y = f2bf(v0[1]); b0.z = f2bf(v0[2]); b0.w = f2bf(v0[3]);
  b1.x = f2bf(v1[0]); b1.y = f2bf(v1[1]); b1.z = f2bf(v1[2]); b1.w = f2bf(v1[3]);
  *(ushort4*)&xb[i] = b0;
  *(ushort4*)&xb[i + 4] = b1;
}

// causal softmax, 2-wide vectorized; combines f16 split-K partials (4 for
// rows < 3584, 3 for rows >= 3584 — all-3-way region); writes f32 probs
// (d_out) + bf16 copy padded to 256-col multiple
__global__ __launch_bounds__(256) void softmax_causal(float* __restrict__ att,
                                                      const u16* __restrict__ p0,
                                                      const u16* __restrict__ p1,
                                                      const u16* __restrict__ p2,
                                                      const u16* __restrict__ p3,
                                                      u16* __restrict__ attB)
{
  int s = blockIdx.x;
  __shared__ float row[S_];
  __shared__ float red[8];
  int tid = threadIdx.x, l = tid & 63, w = tid >> 6;
  int nv = s + 1;
  bool use4 = (s >> 8) < 14;   // rows >= 3584: all tiles 3-way, skip p3
  size_t base = (size_t)s * S_;
  float m = -3.0e38f;
  for (int c = tid * 2; c < nv; c += 512) {
    uint32_t a = *(const uint32_t*)&p0[base + c];
    uint32_t b = *(const uint32_t*)&p1[base + c];
    uint32_t cc = *(const uint32_t*)&p2[base + c];
    uint32_t d = use4 ? *(const uint32_t*)&p3[base + c] : 0u;
    float v0 = h2f_lo(a) + h2f_lo(b) + h2f_lo(cc) + h2f_lo(d);
    row[c] = v0; m = fmaxf(m, v0);
    if (c + 1 < nv) {
      float v1 = h2f_hi(a) + h2f_hi(b) + h2f_hi(cc) + h2f_hi(d);
      row[c + 1] = v1; m = fmaxf(m, v1);
    }
  }
#pragma unroll
  for (int off = 32; off; off >>= 1) m = fmaxf(m, __shfl_xor(m, off, 64));
  if (l == 0) red[w] = m;
  __syncthreads();
  m = fmaxf(fmaxf(red[0], red[1]), fmaxf(red[2], red[3]));
  float sum = 0.f;
  for (int c = tid * 2; c < nv; c += 512) {
    float e0 = __expf(row[c] - m); row[c] = e0; sum += e0;
    if (c + 1 < nv) { float e1 = __expf(row[c + 1] - m); row[c + 1] = e1; sum += e1; }
  }
#pragma unroll
  for (int off = 32; off; off >>= 1) sum += __shfl_xor(sum, off, 64);
  if (l == 0) red[4 + w] = sum;
  __syncthreads();
  sum = red[4] + red[5] + red[6] + red[7];
  float inv = 1.0f / sum;
  int nb = ((s >> 8) + 1) * 256;
  for (int c = tid * 2; c < S_; c += 512) {
    float q0 = (c < nv) ? row[c] * inv : 0.0f;
    float q1 = (c + 1 < nv) ? row[c + 1] * inv : 0.0f;
    f32x2 f2; f2[0] = q0; f2[1] = q1;
    *(f32x2*)&att[base + c] = f2;
    if (c < nb) {
      ushort2 b2; b2.x = f2bf(q0); b2.y = f2bf(q1);
      *(ushort2*)&attB[base + c] = b2;
    }
  }
}

// fused: sum 4 f16 logit partials + bias -> log_softmax -> out (4-wide)
__global__ __launch_bounds__(256) void logsoftmax_k(const u16* __restrict__ p,
                                                    const float* __restrict__ bias,
                                                    float* __restrict__ out)
{
  const int MN = S_ * C_;
  int s = blockIdx.x;
  int tid = threadIdx.x, l = tid & 63, w = tid >> 6;
  __shared__ float red[8];
  size_t base = (size_t)s * C_ + tid * 4;
  ushort4 a = *(const ushort4*)&p[base];
  ushort4 b = *(const ushort4*)&p[MN + base];
  ushort4 c = *(const ushort4*)&p[2 * MN + base];
  ushort4 d = *(const ushort4*)&p[3 * MN + base];
  f32x4 bv = *(const f32x4*)&bias[tid * 4];
  float v[4];
  v[0] = h2f(a.x) + h2f(b.x) + h2f(c.x) + h2f(d.x) + bv[0];
  v[1] = h2f(a.y) + h2f(b.y) + h2f(c.y) + h2f(d.y) + bv[1];
  v[2] = h2f(a.z) + h2f(b.z) + h2f(c.z) + h2f(d.z) + bv[2];
  v[3] = h2f(a.w) + h2f(b.w) + h2f(c.w) + h2f(d.w) + bv[3];
  float m = fmaxf(fmaxf(v[0], v[1]), fmaxf(v[2], v[3]));
#pragma unroll
  for (int off = 32; off; off >>= 1) m = fmaxf(m, __shfl_xor(m, off, 64));
  if (l == 0) red[w] = m;
  __syncthreads();
  m = fmaxf(fmaxf(red[0], red[1]), fmaxf(red[2], red[3]));
  float sum = 0.f;
#pragma unroll
  for (int k = 0; k < 4; ++k) sum += __expf(v[k] - m);
#pragma unroll
  for (int off = 32; off; off >>= 1) sum += __shfl_xor(sum, off, 64);
  if (l == 0) red[4 + w] = sum;
  __syncthreads();
  sum = red[4] + red[5] + red[6] + red[7];
  float lz = m + logf(sum);
  f32x4 o;
#pragma unroll
  for (int k = 0; k < 4; ++k) o[k] = v[k] - lz;
  *(f32x4*)&out[base] = o;
}

extern "C" void kernel_launch(void* const* d_in, const int* in_sizes, int n_in,
                              void* d_out, int out_size, void* d_ws, size_t ws_size,
                              hipStream_t stream) {
  (void)in_sizes; (void)n_in; (void)out_size; (void)ws_size;
  const int*   idx  = (const int*)d_in[0];
  const float* emb  = (const float*)d_in[1];
  const float* pos  = (const float*)d_in[2];
  const float* Wq   = (const float*)d_in[3];
  const float* bq   = (const float*)d_in[4];
  const float* Wk   = (const float*)d_in[5];
  const float* bk   = (const float*)d_in[6];
  const float* Wv   = (const float*)d_in[7];
  const float* bv   = (const float*)d_in[8];
  const float* Wo   = (const float*)d_in[9];
  const float* bo   = (const float*)d_in[10];
  const float* W1   = (const float*)d_in[11];
  const float* b1   = (const float*)d_in[12];
  const float* W2   = (const float*)d_in[13];
  const float* b2   = (const float*)d_in[14];
  const float* Wout = (const float*)d_in[15];
  const float* bout = (const float*)d_in[16];
  float* out = (float*)d_out;

  char* ws = (char*)d_ws;
  const size_t MB = 1024ull * 1024ull;
  u16*  xbf    = (u16*)(ws + 16 * MB);      //  8MB (bf16 residual stream)
  u16*  bufQ   = (u16*)(ws + 24 * MB);      // 32MB  (Q; K at +32MB)
  u16*  bufK   = (u16*)(ws + 56 * MB);      // 32MB
  u16*  bufVT  = (u16*)(ws + 120 * MB);     // 32MB (V^T, direct from QKV)
  u16*  attnB  = (u16*)(ws + 152 * MB);     // 32MB
  u16* WqT   = (u16*)(ws + 200 * MB);       // 8MB each (Wq,Wk,Wv contiguous)
  u16* WkT   = (u16*)(ws + 208 * MB);
  u16* WvT   = (u16*)(ws + 216 * MB);
  u16* WoT   = (u16*)(ws + 224 * MB);
  u16* W1T   = (u16*)(ws + 232 * MB);
  u16* W2T   = (u16*)(ws + 240 * MB);
  u16* WoutT = (u16*)(ws + 248 * MB);       // 2MB
  u16* attP0 = (u16*)(ws + 256 * MB);       // 32MB f16 (tri chunk0)
  u16* attP1 = (u16*)(ws + 288 * MB);       // 32MB f16 (tri chunk1)
  u16* attP2 = (u16*)(ws + 320 * MB);       // 32MB f16 (tri chunk2)
  u16* shP   = (u16*)(ws + 352 * MB);       // 32MB f16 (tri p3 / PV / ks4 / logits)

  const float iscale = 1.0f / 64.0f;
  const int LDSB = 131072;
  hipFuncSetAttribute((const void*)gemm256k,
                      hipFuncAttributeMaxDynamicSharedMemorySize, LDSB);
  hipFuncSetAttribute((const void*)gemm256_qkv,
                      hipFuncAttributeMaxDynamicSharedMemorySize, LDSB);
  hipFuncSetAttribute((const void*)gemm256_tri,
                      hipFuncAttributeMaxDynamicSharedMemorySize, LDSB);
  hipFuncSetAttribute((const void*)gemm256_pv,
                      hipFuncAttributeMaxDynamicSharedMemorySize, LDSB);
  hipFuncSetAttribute((const void*)gemm256_ks4,
                      hipFuncAttributeMaxDynamicSharedMemorySize, LDSB);

  embed_k<<<(S_ * D_) / (256 * 8), 256, 0, stream>>>(idx, emb, pos, xbf);

  for (int layer = 0; layer < L_; ++layer) {
    T7 t7;
    t7.src[0] = Wq + (size_t)layer * D_ * I_; t7.dst[0] = WqT;
    t7.src[1] = Wk + (size_t)layer * D_ * I_; t7.dst[1] = WkT;
    t7.src[2] = Wv + (size_t)layer * D_ * I_; t7.dst[2] = WvT;
    t7.src[3] = Wo + (size_t)layer * I_ * D_; t7.dst[3] = WoT;
    t7.src[4] = W1 + (size_t)layer * D_ * I_; t7.dst[4] = W1T;
    t7.src[5] = W2 + (size_t)layer * I_ * D_; t7.dst[5] = W2T;
    t7.src[6] = Wout;                         t7.dst[6] = WoutT;
    prep_k<<<dim3(64, 16, 8), 256, 0, stream>>>(t7, shP, layer == 0 ? 1 : 0);

    B3 b3;
    b3.b[0] = bq + (size_t)layer * I_;
    b3.b[1] = bk + (size_t)layer * I_;
    b3.b[2] = bv + (size_t)layer * I_;
    gemm256_qkv<<<256, 512, LDSB, stream>>>(xbf, WqT, b3, bufQ, bufVT, D_);

    gemm256_tri<<<512, 512, LDSB, stream>>>(bufQ, bufK, attP0, attP1, attP2,
                                            shP, I_, iscale);

    float* attL = out + (size_t)S_ * C_ + (size_t)layer * S_ * S_;
    softmax_causal<<<S_, 256, 0, stream>>>(attL, attP0, attP1, attP2, shP, attnB);

    gemm256_pv<<<384, 512, LDSB, stream>>>(attnB, bufVT, bufQ, shP);
    combine2pv<<<(S_ / 2) * (I_ / 1024), 256, 0, stream>>>(shP, bufQ);

    gemm256_ks4<<<(S_ / 256) * (D_ / 256) * 4, 512, LDSB, stream>>>(
        bufQ, WoT, shP, S_, D_, I_);
    combine4<<<(S_ * D_) / 1024, 256, 0, stream>>>(
        shP, bo + (size_t)layer * D_, xbf, xbf, S_ * D_, D_);

    gemm256k<<<(S_ / 256) * (I_ / 256), 512, LDSB, stream>>>(
        xbf, W1T, b1 + (size_t)layer * I_, bufK,
        S_, I_, D_, 1.0f, 1, 0, D_);

    gemm256_ks4<<<(S_ / 256) * (D_ / 256) * 4, 512, LDSB, stream>>>(
        bufK, W2T, shP, S_, D_, I_);
    combine4<<<(S_ * D_) / 1024, 256, 0, stream>>>(
        shP, b2 + (size_t)layer * D_, xbf, xbf, S_ * D_, D_);
  }

  gemm256_ks4<<<(S_ / 256) * (C_ / 256) * 4, 512, LDSB, stream>>>(
      xbf, WoutT, shP, S_, C_, D_);
  logsoftmax_k<<<S_, 256, 0, stream>>>(shP, bout, out);
}

// Round 18
// 2060.404 us; speedup vs baseline: 1.0468x; 1.0468x over previous
//
#include <hip/hip_runtime.h>
#include <stdint.h>
#include <math.h>

#define S_ 4096
#define D_ 1024
#define I_ 4096
#define C_ 1024
#define L_ 4

typedef unsigned short u16;
typedef short bf16x8 __attribute__((ext_vector_type(8)));
typedef float f32x4 __attribute__((ext_vector_type(4)));
typedef float f32x2 __attribute__((ext_vector_type(2)));

__device__ __forceinline__ u16 f2bf(float f) {
  union { float f; uint32_t u; } c; c.f = f;
  return (u16)((c.u + 0x7FFFu + ((c.u >> 16) & 1u)) >> 16);
}
__device__ __forceinline__ float bf2f(u16 b) {
  union { uint32_t u; float f; } c; c.u = (uint32_t)b << 16;
  return c.f;
}
__device__ __forceinline__ u16 f2h(float f) {
  _Float16 h = (_Float16)f;
  return *(u16*)&h;
}
__device__ __forceinline__ float h2f(u16 b) {
  _Float16 h = *(_Float16*)&b;
  return (float)h;
}
__device__ __forceinline__ float h2f_lo(uint32_t u) { return h2f((u16)(u & 0xffffu)); }
__device__ __forceinline__ float h2f_hi(uint32_t u) { return h2f((u16)(u >> 16)); }

__device__ __forceinline__ void gll16(const void* g, void* l) {
  __builtin_amdgcn_global_load_lds(
      (__attribute__((address_space(1))) void*)(g),
      (__attribute__((address_space(3))) void*)(l), 16, 0, 0);
}

#define BAR() asm volatile("s_barrier" ::: "memory")
#define WAITV(n) asm volatile("s_waitcnt vmcnt(" #n ")" ::: "memory")

// bijective XCD swizzle (m204)
__device__ __forceinline__ int xcd_swz(int orig, int nwg) {
  int q8 = nwg >> 3, r8 = nwg & 7;
  int xcd = orig & 7, rem = orig >> 3;
  return (xcd < r8 ? xcd * (q8 + 1) : r8 * (q8 + 1) + (xcd - r8) * q8) + rem;
}

// triangular tile decode: tidx -> (br, bc), bc <= br
__device__ __forceinline__ void tri_decode(int tidx, int& br, int& bc) {
  br = (int)((sqrtf(8.0f * (float)tidx + 1.0f) - 1.0f) * 0.5f);
  while ((br + 1) * (br + 2) / 2 <= tidx) ++br;
  while (br * (br + 1) / 2 > tidx) --br;
  bc = tidx - br * (br + 1) / 2;
}

// ---------------- 256x256 8-phase body (T1+T2+T3+T4+T5) ----------------
// 512 threads = 8 waves (2M x 4N), per-wave C = 128x64, BK = 64.
// LDS: A[2 par][2 half][128x64], B same = 128 KiB. XOR-octet swizzle.
// NOTE: 128 KiB LDS -> 1 block/CU; dispatch wall = ceil(nblocks/256) rounds.
// Window t: ph1 stages B-h1(t+1); ph2: A-h0(t+2); ph3: A-h1(t+2); ph4: B-h0(t+2).
// vmcnt(6) at window boundary retires through B-h1(t+1). Requires t1-t0 >= 2.
// Outputs (u16 only): outU row-major (bf16 if isBF else f16) via LDS-bounce
// coalesced epilogue, or outT: bf16 TRANSPOSED (outT[col][row], ld=ldT).
__device__ __forceinline__ void gemm256_body(
    u16* sA, u16* sB,
    const u16* __restrict__ A, const u16* __restrict__ Bt,
    const float* __restrict__ bias,
    u16* __restrict__ outU, int isBF,
    u16* __restrict__ outT, int ldT,
    int N, int K, float scale, int relu,
    int row0, int col0, int t0, int t1)
{
  int tid = threadIdx.x, l = tid & 63;
  int w = tid >> 6;
  int wr = w >> 2, wc = w & 3;
  int lrow = l & 15, lq = l >> 4;
  int hb = wc >> 1;
  int rx = lrow & 7;

  const u16* ap[2]; const u16* bp[2]; int dst[2];
#pragma unroll
  for (int u = 0; u < 2; ++u) {
    int c = u * 512 + tid;
    int row = c >> 3;
    int oct = (c & 7) ^ (row & 7);
    ap[u] = A + (size_t)(row0 + row) * K + oct * 8;
    bp[u] = Bt + (size_t)(col0 + row) * K + oct * 8;
    dst[u] = c * 8;
  }

#define STAGE_A(par, hh, t)                                                     \
  { _Pragma("unroll") for (int u = 0; u < 2; ++u)                               \
      gll16(ap[u] + (size_t)(hh) * 128 * K + (t) * 64,                          \
            &sA[((par) * 2 + (hh)) * 8192 + dst[u]]); }
#define STAGE_B(par, hh, t)                                                     \
  { _Pragma("unroll") for (int u = 0; u < 2; ++u)                               \
      gll16(bp[u] + (size_t)(hh) * 128 * K + (t) * 64,                          \
            &sB[((par) * 2 + (hh)) * 8192 + dst[u]]); }
#define LD_A(DST, par, mh)                                                      \
  { _Pragma("unroll") for (int mi = 0; mi < 4; ++mi)                            \
    _Pragma("unroll") for (int kc = 0; kc < 2; ++kc)                            \
      DST[mi][kc] = *(const bf16x8*)&sA[((par) * 2 + wr) * 8192 +               \
          ((mh) * 64 + mi * 16 + lrow) * 64 + (((kc * 4 + lq) ^ rx) * 8)]; }
#define LD_B(DST, par, nh)                                                      \
  { _Pragma("unroll") for (int nj = 0; nj < 2; ++nj)                            \
    _Pragma("unroll") for (int kc = 0; kc < 2; ++kc)                            \
      DST[nj][kc] = *(const bf16x8*)&sB[((par) * 2 + hb) * 8192 +               \
          ((wc & 1) * 64 + (nh) * 32 + nj * 16 + lrow) * 64 +                   \
          (((kc * 4 + lq) ^ rx) * 8)]; }

  f32x4 acc[8][4];
#pragma unroll
  for (int i = 0; i < 8; ++i)
#pragma unroll
    for (int j = 0; j < 4; ++j) {
      acc[i][j][0] = 0.f; acc[i][j][1] = 0.f; acc[i][j][2] = 0.f; acc[i][j][3] = 0.f;
    }

#define MM(AF, MB, NB)                                                          \
  { __builtin_amdgcn_s_setprio(1);                                             \
    _Pragma("unroll") for (int kc = 0; kc < 2; ++kc)                            \
    _Pragma("unroll") for (int mi = 0; mi < 4; ++mi)                            \
    _Pragma("unroll") for (int nj = 0; nj < 2; ++nj)                            \
      acc[(MB) + mi][(NB) + nj] = __builtin_amdgcn_mfma_f32_16x16x32_bf16(      \
          AF[mi][kc], bfv[nj][kc], acc[(MB) + mi][(NB) + nj], 0, 0, 0);         \
    __builtin_amdgcn_s_setprio(0); }

  bf16x8 afA[4][2], afB[4][2], bfv[2][2];

  STAGE_A(0, 0, t0); STAGE_A(0, 1, t0); STAGE_B(0, 0, t0); STAGE_B(0, 1, t0);
  STAGE_A(1, 0, t0 + 1); STAGE_A(1, 1, t0 + 1); STAGE_B(1, 0, t0 + 1);
  WAITV(6);
  BAR();

  for (int t = t0; t < t1; ++t) {
    int p = (t - t0) & 1;
    LD_A(afA, p, 0);
    LD_B(bfv, p, 0);
    LD_A(afB, p, 1);
    if (t + 1 < t1) STAGE_B(p ^ 1, 1, t + 1);
    BAR();
    MM(afA, 0, 0);
    BAR();
    if (t + 2 < t1) STAGE_A(p, 0, t + 2);
    BAR();
    MM(afB, 4, 0);
    BAR();
    LD_B(bfv, p, 1);
    if (t + 2 < t1) STAGE_A(p, 1, t + 2);
    BAR();
    MM(afB, 4, 2);
    BAR();
    if (t + 2 < t1) STAGE_B(p, 0, t + 2);
    BAR();
    MM(afA, 0, 2);
    if (t + 2 < t1) { WAITV(6); } else { WAITV(0); }
    BAR();
  }
#undef STAGE_A
#undef STAGE_B
#undef LD_A
#undef LD_B
#undef MM

  float biasv[4] = {0.f, 0.f, 0.f, 0.f};
  if (bias) {
#pragma unroll
    for (int j = 0; j < 4; ++j) biasv[j] = bias[col0 + wc * 64 + j * 16 + lrow];
  }

  if (outT) {
    // transposed bf16 epilogue via LDS bounce (verified round 10).
    u16* tlds = sA;  // [128 cols][264 rows]
    int myhalf = wc >> 1;
    int colb = tid >> 5;
    int sub = tid & 31;
#pragma unroll
    for (int half = 0; half < 2; ++half) {
      BAR();
      if (myhalf == half) {
#pragma unroll
        for (int i = 0; i < 8; ++i)
#pragma unroll
          for (int r = 0; r < 4; ++r)
#pragma unroll
            for (int j = 0; j < 4; ++j) {
              int cl = (wc * 64 + j * 16 + lrow) & 127;
              int rowl = wr * 128 + i * 16 + lq * 4 + r;
              tlds[cl * 264 + rowl] = f2bf(acc[i][j][r] + biasv[j]);
            }
      }
      BAR();
#pragma unroll
      for (int it = 0; it < 8; ++it) {
        int cl = it * 16 + colb;
        size_t gb = (size_t)(col0 + half * 128 + cl) * ldT + row0 + sub * 8;
        bf16x8 v = *(const bf16x8*)&tlds[cl * 264 + sub * 8];
        *(bf16x8*)&outT[gb] = v;
      }
    }
    return;
  }

  // row-major u16 epilogue via LDS bounce
  u16* tlds = sA;
  int rl0 = tid >> 5;   // 0..15
  int ch = tid & 31;    // 0..31
#pragma unroll
  for (int half = 0; half < 2; ++half) {
    BAR();
    if (wr == half) {
#pragma unroll
      for (int i = 0; i < 8; ++i)
#pragma unroll
        for (int r = 0; r < 4; ++r)
#pragma unroll
          for (int j = 0; j < 4; ++j) {
            int rowl = i * 16 + lq * 4 + r;
            int cl = wc * 64 + j * 16 + lrow;
            float v = acc[i][j][r] * scale + biasv[j];
            if (relu) v = fmaxf(v, 0.f);
            tlds[rowl * 264 + cl] = isBF ? f2bf(v) : f2h(v);
          }
    }
    BAR();
#pragma unroll
    for (int it = 0; it < 8; ++it) {
      int rowl = it * 16 + rl0;
      size_t gb = (size_t)(row0 + half * 128 + rowl) * N + col0 + ch * 8;
      bf16x8 v = *(const bf16x8*)&tlds[rowl * 264 + ch * 8];
      *(bf16x8*)&outU[gb] = v;
    }
  }
}

// plain / K-ranged (flags: 1 relu), K-range [k0,k1), bf16 out
__global__ __launch_bounds__(512, 2) void gemm256k(
    const u16* __restrict__ A, const u16* __restrict__ Bt,
    const float* __restrict__ bias, u16* __restrict__ outB,
    int M, int N, int K, float scale, int flags, int k0, int k1)
{
  extern __shared__ char smem[];
  int wg = xcd_swz(blockIdx.x, gridDim.x);
  int nbx = N / 256;
  int br = wg / nbx, bc = wg % nbx;
  gemm256_body((u16*)smem, (u16*)smem + 32768, A, Bt, bias, outB, 1,
               nullptr, 0, N, K, scale, flags & 1, br * 256, bc * 256,
               k0 / 64, k1 / 64);
}

// fused QKV: grid 3*256; z = wg>>8 selects {Q,K,V}. V (z==2) is emitted
// TRANSPOSED directly to vT via the LDS-bounce epilogue (no row-major V).
// (r17 lesson: separate-z blocks beat intra-block 3x serialization — the
// shared A-panel is only 8MB and L2-resident anyway.)
struct B3 { const float* b[3]; };
__global__ __launch_bounds__(512, 2) void gemm256_qkv(
    const u16* __restrict__ A, const u16* __restrict__ BtBase,
    B3 b3, u16* __restrict__ outQK, u16* __restrict__ vT, int K)
{
  extern __shared__ char smem[];
  int wg = xcd_swz(blockIdx.x, gridDim.x);
  int z = wg >> 8;
  int tile = wg & 255;
  int br = tile >> 4, bc = tile & 15;
  if (z < 2) {
    gemm256_body((u16*)smem, (u16*)smem + 32768, A,
                 BtBase + (size_t)z * I_ * D_, b3.b[z],
                 outQK + (size_t)z * S_ * I_, 1, nullptr, 0,
                 I_, K, 1.0f, 0, br * 256, bc * 256, 0, K / 64);
  } else {
    gemm256_body((u16*)smem, (u16*)smem + 32768, A,
                 BtBase + (size_t)2 * I_ * D_, b3.b[2],
                 nullptr, 1, vT, S_,
                 I_, K, 1.0f, 0, br * 256, bc * 256, 0, K / 64);
  }
}

// triangular causal scores, balanced 512-block split (r13/r14): tiles 0..103
// 4-way (16 kt, p0..p3); tiles 104..135 3-way (21/21/22 kt, p0..p2).
// Only tile 104 (br13 diag) needs its p3 rect zeroed (rows>=3584 are all
// 3-way and softmax skips p3 there). 3-way blocks interleaved 6-per-32-wg.
__global__ __launch_bounds__(512, 2) void gemm256_tri(
    const u16* __restrict__ A, const u16* __restrict__ Bt,
    u16* __restrict__ p0, u16* __restrict__ p1, u16* __restrict__ p2,
    u16* __restrict__ p3, int K, float scale)
{
  extern __shared__ char smem[];
  int wg = xcd_swz(blockIdx.x, gridDim.x);   // grid 512
  int c32 = wg >> 5, off = wg & 31;
  int tidx, t0, t1;
  u16* o;
  if (off < 6) {
    int i3 = c32 * 6 + off;        // 0..95
    tidx = 104 + i3 / 3;
    int chk = i3 % 3;
    t0 = (chk == 0) ? 0 : (chk == 1 ? 21 : 42);
    t1 = (chk == 0) ? 21 : (chk == 1 ? 42 : 64);
    o = (chk == 0) ? p0 : (chk == 1 ? p1 : p2);
  } else {
    int i4 = c32 * 26 + (off - 6); // 0..415
    tidx = i4 >> 2;
    int chk = i4 & 3;
    t0 = chk * 16; t1 = t0 + 16;
    o = (chk == 0) ? p0 : (chk == 1 ? p1 : (chk == 2 ? p2 : p3));
  }
  int br, bc;
  tri_decode(tidx, br, bc);
  gemm256_body((u16*)smem, (u16*)smem + 32768, A, Bt, nullptr,
               o, 0, nullptr, 0,
               S_, K, scale, 0, br * 256, bc * 256, t0, t1);
}

// PV hybrid, LPT-ordered (longest blocks first).
__global__ __launch_bounds__(512, 2) void gemm256_pv(
    const u16* __restrict__ A, const u16* __restrict__ Bt,
    u16* __restrict__ outB, u16* __restrict__ pvH)
{
  extern __shared__ char smem[];
  int wg = xcd_swz(blockIdx.x, gridDim.x);   // grid 384
  int s0, br, dir;
  if      (wg < 32)  { s0 = 0;   br = 15; dir = 0; }
  else if (wg < 48)  { s0 = 32;  br = 7;  dir = 1; }
  else if (wg < 80)  { s0 = 48;  br = 14; dir = 0; }
  else if (wg < 112) { s0 = 80;  br = 13; dir = 0; }
  else if (wg < 128) { s0 = 112; br = 6;  dir = 1; }
  else if (wg < 160) { s0 = 128; br = 12; dir = 0; }
  else if (wg < 192) { s0 = 160; br = 11; dir = 0; }
  else if (wg < 208) { s0 = 192; br = 5;  dir = 1; }
  else if (wg < 240) { s0 = 208; br = 10; dir = 0; }
  else if (wg < 272) { s0 = 240; br = 9;  dir = 0; }
  else if (wg < 288) { s0 = 272; br = 4;  dir = 1; }
  else if (wg < 320) { s0 = 288; br = 8;  dir = 0; }
  else if (wg < 336) { s0 = 320; br = 3;  dir = 1; }
  else if (wg < 352) { s0 = 336; br = 2;  dir = 1; }
  else if (wg < 368) { s0 = 352; br = 1;  dir = 1; }
  else               { s0 = 368; br = 0;  dir = 1; }
  int u = wg - s0;
  if (dir) {
    int bc = u;
    gemm256_body((u16*)smem, (u16*)smem + 32768, A, Bt, nullptr,
                 outB, 1, nullptr, 0, I_, S_, 1.0f, 0,
                 br * 256, bc * 256, 0, (br + 1) * 4);
  } else {
    int bc = u >> 1;
    int chunk = u & 1;
    int lim = (br + 1) * 4;
    int half = lim >> 1;
    u16* o = pvH + (size_t)chunk * (S_ / 2) * I_ - (size_t)2048 * I_;
    gemm256_body((u16*)smem, (u16*)smem + 32768, A, Bt, nullptr,
                 o, 0, nullptr, 0, I_, S_, 1.0f, 0,
                 br * 256, bc * 256, chunk ? half : 0, chunk ? lim : half);
  }
}

// combine PV bottom-half f16 partials -> bf16
__global__ __launch_bounds__(256) void combine2pv(
    const u16* __restrict__ pvH, u16* __restrict__ outB)
{
  const int MN = (S_ / 2) * I_;
  int i = (blockIdx.x * 256 + threadIdx.x) * 4;
  ushort4 a = *(const ushort4*)&pvH[i];
  ushort4 b = *(const ushort4*)&pvH[MN + i];
  ushort4 o;
  o.x = f2bf(h2f(a.x) + h2f(b.x));
  o.y = f2bf(h2f(a.y) + h2f(b.y));
  o.z = f2bf(h2f(a.z) + h2f(b.z));
  o.w = f2bf(h2f(a.w) + h2f(b.w));
  *(ushort4*)&outB[(size_t)2048 * I_ + i] = o;
}

// 4-way K-split f16 partials: grid = ntiles*4
__global__ __launch_bounds__(512, 2) void gemm256_ks4(
    const u16* __restrict__ A, const u16* __restrict__ Bt,
    u16* __restrict__ pOut, int M, int N, int K)
{
  extern __shared__ char smem[];
  int wg = xcd_swz(blockIdx.x, gridDim.x);
  int chunk = wg & 3;
  int tile = wg >> 2;
  int nbx = N / 256;
  int br = tile / nbx, bc = tile % nbx;
  u16* o = pOut + (size_t)chunk * M * N;
  int kq = K / 4;
  gemm256_body((u16*)smem, (u16*)smem + 32768, A, Bt, nullptr,
               o, 0, nullptr, 0, N, K, 1.0f, 0,
               br * 256, bc * 256, (chunk * kq) / 64, ((chunk + 1) * kq) / 64);
}

// combine 4 f16 K-split partials + bias + bf16 resid -> bf16 (N power of 2)
__global__ __launch_bounds__(256) void combine4(
    const u16* __restrict__ p, const float* __restrict__ bias,
    const u16* __restrict__ residB, u16* __restrict__ outB, int MN, int N)
{
  int i = (blockIdx.x * 256 + threadIdx.x) * 4;
  ushort4 a = *(const ushort4*)&p[i];
  ushort4 b = *(const ushort4*)&p[MN + i];
  ushort4 c = *(const ushort4*)&p[2 * MN + i];
  ushort4 d = *(const ushort4*)&p[3 * MN + i];
  ushort4 rb = *(const ushort4*)&residB[i];
  f32x4 v;
  v[0] = h2f(a.x) + h2f(b.x) + h2f(c.x) + h2f(d.x) + bf2f(rb.x);
  v[1] = h2f(a.y) + h2f(b.y) + h2f(c.y) + h2f(d.y) + bf2f(rb.y);
  v[2] = h2f(a.z) + h2f(b.z) + h2f(c.z) + h2f(d.z) + bf2f(rb.z);
  v[3] = h2f(a.w) + h2f(b.w) + h2f(c.w) + h2f(d.w) + bf2f(rb.w);
  int col = i & (N - 1);
  v += *(const f32x4*)&bias[col];
  ushort4 o;
  o.x = f2bf(v[0]); o.y = f2bf(v[1]); o.z = f2bf(v[2]); o.w = f2bf(v[3]);
  *(ushort4*)&outB[i] = o;
}

// per-layer prep: z 0..5 weight transpose+convert (64x64 tiles);
// z==6 Wout transpose (layer 0 only, doWout flag); z==7 fillp3 (zero the p3
// rect of tile 104 only — br13 diag; rows>=3584 skip p3 in softmax).
struct T7 {
  const float* src[7];
  u16* dst[7];
};

__global__ __launch_bounds__(256) void prep_k(T7 a, u16* __restrict__ p3,
                                              int doWout) {
  int z = blockIdx.z;
  if (z == 7) {
    int b = blockIdx.y * gridDim.x + blockIdx.x;
    if (b >= 32) return;
    int row = 13 * 256 + b * 8 + (threadIdx.x >> 5);
    int col = 13 * 256 + (threadIdx.x & 31) * 8;
    ushort4 z4 = {0, 0, 0, 0};
    *(ushort4*)&p3[(size_t)row * S_ + col] = z4;
    *(ushort4*)&p3[(size_t)row * S_ + col + 4] = z4;
    return;
  }
  if (z == 6 && !doWout) return;
  __shared__ float tile[64][65];
  int R, C;
  if (z == 6) { R = D_; C = C_; }
  else if (z == 3 || z == 5) { R = I_; C = D_; }
  else { R = D_; C = I_; }
  int bid = blockIdx.y * gridDim.x + blockIdx.x;
  int nbx = C / 64;
  if (bid >= nbx * (R / 64)) return;
  int bx = bid % nbx, by = bid / nbx;
  const float* src = a.src[z];
  u16* dst = a.dst[z];
  int c0 = bx * 64, r0 = by * 64;
  int tx = threadIdx.x & 63, ty = threadIdx.x >> 6;
#pragma unroll
  for (int i = 0; i < 64; i += 4)
    tile[ty + i][tx] = src[(size_t)(r0 + ty + i) * C + c0 + tx];
  __syncthreads();
#pragma unroll
  for (int i = 0; i < 64; i += 4)
    dst[(size_t)(c0 + ty + i) * R + r0 + tx] = f2bf(tile[tx][ty + i]);
}

// embed: 8 elems/thread, bf16 out only
__global__ __launch_bounds__(256) void embed_k(const int* __restrict__ idx,
                                               const float* __restrict__ emb,
                                               const float* __restrict__ pos,
                                               u16* __restrict__ xb)
{
  int i = (blockIdx.x * 256 + threadIdx.x) * 8;
  int s = i >> 10;          // / D_
  int d = i & (D_ - 1);
  const float* e = emb + (size_t)idx[s] * D_ + d;
  const float* p = pos + (size_t)s * D_ + d;
  f32x4 v0 = *(const f32x4*)e + *(const f32x4*)p;
  f32x4 v1 = *(const f32x4*)(e + 4) + *(const f32x4*)(p + 4);
  ushort4 b0, b1;
  b0.x = f2bf(v0[0]); b0.y = f2bf(v0[1]); b0.z = f2bf(v0[2]); b0.w = f2bf(v0[3]);
  b1.x = f2bf(v1[0]); b1.y = f2bf(v1[1]); b1.z = f2bf(v1[2]); b1.w = f2bf(v1[3]);
  *(ushort4*)&xb[i] = b0;
  *(ushort4*)&xb[i + 4] = b1;
}

// causal softmax, 2-wide vectorized; combines f16 split-K partials (4 for
// rows < 3584, 3 for rows >= 3584 — all-3-way region); writes f32 probs
// (d_out) + bf16 copy padded to 256-col multiple
__global__ __launch_bounds__(256) void softmax_causal(float* __restrict__ att,
                                                      const u16* __restrict__ p0,
                                                      const u16* __restrict__ p1,
                                                      const u16* __restrict__ p2,
                                                      const u16* __restrict__ p3,
                                                      u16* __restrict__ attB)
{
  int s = blockIdx.x;
  __shared__ float row[S_];
  __shared__ float red[8];
  int tid = threadIdx.x, l = tid & 63, w = tid >> 6;
  int nv = s + 1;
  bool use4 = (s >> 8) < 14;   // rows >= 3584: all tiles 3-way, skip p3
  size_t base = (size_t)s * S_;
  float m = -3.0e38f;
  for (int c = tid * 2; c < nv; c += 512) {
    uint32_t a = *(const uint32_t*)&p0[base + c];
    uint32_t b = *(const uint32_t*)&p1[base + c];
    uint32_t cc = *(const uint32_t*)&p2[base + c];
    uint32_t d = use4 ? *(const uint32_t*)&p3[base + c] : 0u;
    float v0 = h2f_lo(a) + h2f_lo(b) + h2f_lo(cc) + h2f_lo(d);
    row[c] = v0; m = fmaxf(m, v0);
    if (c + 1 < nv) {
      float v1 = h2f_hi(a) + h2f_hi(b) + h2f_hi(cc) + h2f_hi(d);
      row[c + 1] = v1; m = fmaxf(m, v1);
    }
  }
#pragma unroll
  for (int off = 32; off; off >>= 1) m = fmaxf(m, __shfl_xor(m, off, 64));
  if (l == 0) red[w] = m;
  __syncthreads();
  m = fmaxf(fmaxf(red[0], red[1]), fmaxf(red[2], red[3]));
  float sum = 0.f;
  for (int c = tid * 2; c < nv; c += 512) {
    float e0 = __expf(row[c] - m); row[c] = e0; sum += e0;
    if (c + 1 < nv) { float e1 = __expf(row[c + 1] - m); row[c + 1] = e1; sum += e1; }
  }
#pragma unroll
  for (int off = 32; off; off >>= 1) sum += __shfl_xor(sum, off, 64);
  if (l == 0) red[4 + w] = sum;
  __syncthreads();
  sum = red[4] + red[5] + red[6] + red[7];
  float inv = 1.0f / sum;
  int nb = ((s >> 8) + 1) * 256;
  for (int c = tid * 2; c < S_; c += 512) {
    float q0 = (c < nv) ? row[c] * inv : 0.0f;
    float q1 = (c + 1 < nv) ? row[c + 1] * inv : 0.0f;
    f32x2 f2; f2[0] = q0; f2[1] = q1;
    *(f32x2*)&att[base + c] = f2;
    if (c < nb) {
      ushort2 b2; b2.x = f2bf(q0); b2.y = f2bf(q1);
      *(ushort2*)&attB[base + c] = b2;
    }
  }
}

// fused: sum 4 f16 logit partials + bias -> log_softmax -> out (4-wide)
__global__ __launch_bounds__(256) void logsoftmax_k(const u16* __restrict__ p,
                                                    const float* __restrict__ bias,
                                                    float* __restrict__ out)
{
  const int MN = S_ * C_;
  int s = blockIdx.x;
  int tid = threadIdx.x, l = tid & 63, w = tid >> 6;
  __shared__ float red[8];
  size_t base = (size_t)s * C_ + tid * 4;
  ushort4 a = *(const ushort4*)&p[base];
  ushort4 b = *(const ushort4*)&p[MN + base];
  ushort4 c = *(const ushort4*)&p[2 * MN + base];
  ushort4 d = *(const ushort4*)&p[3 * MN + base];
  f32x4 bv = *(const f32x4*)&bias[tid * 4];
  float v[4];
  v[0] = h2f(a.x) + h2f(b.x) + h2f(c.x) + h2f(d.x) + bv[0];
  v[1] = h2f(a.y) + h2f(b.y) + h2f(c.y) + h2f(d.y) + bv[1];
  v[2] = h2f(a.z) + h2f(b.z) + h2f(c.z) + h2f(d.z) + bv[2];
  v[3] = h2f(a.w) + h2f(b.w) + h2f(c.w) + h2f(d.w) + bv[3];
  float m = fmaxf(fmaxf(v[0], v[1]), fmaxf(v[2], v[3]));
#pragma unroll
  for (int off = 32; off; off >>= 1) m = fmaxf(m, __shfl_xor(m, off, 64));
  if (l == 0) red[w] = m;
  __syncthreads();
  m = fmaxf(fmaxf(red[0], red[1]), fmaxf(red[2], red[3]));
  float sum = 0.f;
#pragma unroll
  for (int k = 0; k < 4; ++k) sum += __expf(v[k] - m);
#pragma unroll
  for (int off = 32; off; off >>= 1) sum += __shfl_xor(sum, off, 64);
  if (l == 0) red[4 + w] = sum;
  __syncthreads();
  sum = red[4] + red[5] + red[6] + red[7];
  float lz = m + logf(sum);
  f32x4 o;
#pragma unroll
  for (int k = 0; k < 4; ++k) o[k] = v[k] - lz;
  *(f32x4*)&out[base] = o;
}

extern "C" void kernel_launch(void* const* d_in, const int* in_sizes, int n_in,
                              void* d_out, int out_size, void* d_ws, size_t ws_size,
                              hipStream_t stream) {
  (void)in_sizes; (void)n_in; (void)out_size; (void)ws_size;
  const int*   idx  = (const int*)d_in[0];
  const float* emb  = (const float*)d_in[1];
  const float* pos  = (const float*)d_in[2];
  const float* Wq   = (const float*)d_in[3];
  const float* bq   = (const float*)d_in[4];
  const float* Wk   = (const float*)d_in[5];
  const float* bk   = (const float*)d_in[6];
  const float* Wv   = (const float*)d_in[7];
  const float* bv   = (const float*)d_in[8];
  const float* Wo   = (const float*)d_in[9];
  const float* bo   = (const float*)d_in[10];
  const float* W1   = (const float*)d_in[11];
  const float* b1   = (const float*)d_in[12];
  const float* W2   = (const float*)d_in[13];
  const float* b2   = (const float*)d_in[14];
  const float* Wout = (const float*)d_in[15];
  const float* bout = (const float*)d_in[16];
  float* out = (float*)d_out;

  char* ws = (char*)d_ws;
  const size_t MB = 1024ull * 1024ull;
  u16*  xbf    = (u16*)(ws + 16 * MB);      //  8MB (bf16 residual stream)
  u16*  bufQ   = (u16*)(ws + 24 * MB);      // 32MB  (Q; K at +32MB)
  u16*  bufK   = (u16*)(ws + 56 * MB);      // 32MB
  u16*  bufVT  = (u16*)(ws + 120 * MB);     // 32MB (V^T, direct from QKV)
  u16*  attnB  = (u16*)(ws + 152 * MB);     // 32MB
  u16* WqT   = (u16*)(ws + 200 * MB);       // 8MB each (Wq,Wk,Wv contiguous)
  u16* WkT   = (u16*)(ws + 208 * MB);
  u16* WvT   = (u16*)(ws + 216 * MB);
  u16* WoT   = (u16*)(ws + 224 * MB);
  u16* W1T   = (u16*)(ws + 232 * MB);
  u16* W2T   = (u16*)(ws + 240 * MB);
  u16* WoutT = (u16*)(ws + 248 * MB);       // 2MB
  u16* attP0 = (u16*)(ws + 256 * MB);       // 32MB f16 (tri chunk0)
  u16* attP1 = (u16*)(ws + 288 * MB);       // 32MB f16 (tri chunk1)
  u16* attP2 = (u16*)(ws + 320 * MB);       // 32MB f16 (tri chunk2)
  u16* shP   = (u16*)(ws + 352 * MB);       // 32MB f16 (tri p3 / PV / ks4 / logits)

  const float iscale = 1.0f / 64.0f;
  const int LDSB = 131072;
  hipFuncSetAttribute((const void*)gemm256k,
                      hipFuncAttributeMaxDynamicSharedMemorySize, LDSB);
  hipFuncSetAttribute((const void*)gemm256_qkv,
                      hipFuncAttributeMaxDynamicSharedMemorySize, LDSB);
  hipFuncSetAttribute((const void*)gemm256_tri,
                      hipFuncAttributeMaxDynamicSharedMemorySize, LDSB);
  hipFuncSetAttribute((const void*)gemm256_pv,
                      hipFuncAttributeMaxDynamicSharedMemorySize, LDSB);
  hipFuncSetAttribute((const void*)gemm256_ks4,
                      hipFuncAttributeMaxDynamicSharedMemorySize, LDSB);
  const int G_SQ = (S_ / 256) * (I_ / 256);            // 256

  embed_k<<<(S_ * D_) / (256 * 8), 256, 0, stream>>>(idx, emb, pos, xbf);

  for (int layer = 0; layer < L_; ++layer) {
    T7 t7;
    t7.src[0] = Wq + (size_t)layer * D_ * I_; t7.dst[0] = WqT;
    t7.src[1] = Wk + (size_t)layer * D_ * I_; t7.dst[1] = WkT;
    t7.src[2] = Wv + (size_t)layer * D_ * I_; t7.dst[2] = WvT;
    t7.src[3] = Wo + (size_t)layer * I_ * D_; t7.dst[3] = WoT;
    t7.src[4] = W1 + (size_t)layer * D_ * I_; t7.dst[4] = W1T;
    t7.src[5] = W2 + (size_t)layer * I_ * D_; t7.dst[5] = W2T;
    t7.src[6] = Wout;                         t7.dst[6] = WoutT;
    prep_k<<<dim3(64, 16, 8), 256, 0, stream>>>(t7, shP, layer == 0 ? 1 : 0);

    B3 b3;
    b3.b[0] = bq + (size_t)layer * I_;
    b3.b[1] = bk + (size_t)layer * I_;
    b3.b[2] = bv + (size_t)layer * I_;
    gemm256_qkv<<<3 * G_SQ, 512, LDSB, stream>>>(xbf, WqT, b3, bufQ, bufVT, D_);

    gemm256_tri<<<512, 512, LDSB, stream>>>(bufQ, bufK, attP0, attP1, attP2,
                                            shP, I_, iscale);

    float* attL = out + (size_t)S_ * C_ + (size_t)layer * S_ * S_;
    softmax_causal<<<S_, 256, 0, stream>>>(attL, attP0, attP1, attP2, shP, attnB);

    gemm256_pv<<<384, 512, LDSB, stream>>>(attnB, bufVT, bufQ, shP);
    combine2pv<<<(S_ / 2) * (I_ / 1024), 256, 0, stream>>>(shP, bufQ);

    gemm256_ks4<<<(S_ / 256) * (D_ / 256) * 4, 512, LDSB, stream>>>(
        bufQ, WoT, shP, S_, D_, I_);
    combine4<<<(S_ * D_) / 1024, 256, 0, stream>>>(
        shP, bo + (size_t)layer * D_, xbf, xbf, S_ * D_, D_);

    gemm256k<<<G_SQ, 512, LDSB, stream>>>(
        xbf, W1T, b1 + (size_t)layer * I_, bufK,
        S_, I_, D_, 1.0f, 1, 0, D_);

    gemm256_ks4<<<(S_ / 256) * (D_ / 256) * 4, 512, LDSB, stream>>>(
        bufK, W2T, shP, S_, D_, I_);
    combine4<<<(S_ * D_) / 1024, 256, 0, stream>>>(
        shP, b2 + (size_t)layer * D_, xbf, xbf, S_ * D_, D_);
  }

  gemm256_ks4<<<(S_ / 256) * (C_ / 256) * 4, 512, LDSB, stream>>>(
      xbf, WoutT, shP, S_, C_, D_);
  logsoftmax_k<<<S_, 256, 0, stream>>>(shP, bout, out);
}